// Round 4
// baseline (520.439 us; speedup 1.0000x reference)
//
#include <hip/hip_runtime.h>
#include <hip/hip_bf16.h>

// Problem constants (B=4, S=2048, H=2048, E=8, K=2)
#define T_TOK 8192
#define H_DIM 2048
#define NE 8

typedef float f32x4 __attribute__((ext_vector_type(4)));
typedef short s16x8 __attribute__((ext_vector_type(8)));

typedef __attribute__((address_space(3))) unsigned int lds_uint;
typedef __attribute__((address_space(1))) const unsigned int glob_uint;

static __device__ __forceinline__ void async_ld16(const void* g, void* l) {
    // 64 lanes x 16B: global per-lane address -> LDS (wave-uniform base + lane*16)
    __builtin_amdgcn_global_load_lds((glob_uint*)g, (lds_uint*)l, 16, 0, 0);
}

static __device__ __forceinline__ unsigned short f32_to_bf16(float f) {
    unsigned int u = __builtin_bit_cast(unsigned int, f);
    unsigned int r = (u + 0x7FFFu + ((u >> 16) & 1u)) >> 16;
    return (unsigned short)r;
}

static __device__ __forceinline__ unsigned int pack_bf16x2(float lo, float hi) {
    return (unsigned int)f32_to_bf16(lo) | ((unsigned int)f32_to_bf16(hi) << 16);
}

// ---------------------------------------------------------------------------
// Fused pre-kernel: one grid, three independent block ranges that previously
// ran as three serialized launches (router / W-convert / out-zero). They now
// overlap; total time ~= combined HBM traffic / BW (~570 MB -> ~105 us).
//   blocks [0,512):        router (16 tokens/block, 64 KiB gate LDS)
//   blocks [512,2560):     W fp32 -> bf16 convert (grid-stride, 32B ld/16B st)
//   blocks [2560,3584):    zero out[] (uint4 stores)
// cnt[] is zeroed by a hipMemsetAsync BEFORE this kernel (stream-ordered),
// so the router's atomicAdd compaction is safe.
// ---------------------------------------------------------------------------
#define RT_NB 512
#define PREP_NB 2048
#define ZERO_NB 1024

__global__ __launch_bounds__(256) void pre_kernel(
        const float* __restrict__ x, const float* __restrict__ gate,
        const float* __restrict__ w,
        unsigned short* __restrict__ xb, unsigned short* __restrict__ wb,
        float* __restrict__ logits, float* __restrict__ out,
        int* __restrict__ cnt, int* __restrict__ list, float* __restrict__ wl) {
    __shared__ float4 gs[NE * H_DIM / 4];  // 64 KiB (used by router blocks only)
    __shared__ int aExp[32];
    __shared__ float aW[32];

    const int bx = blockIdx.x;
    const int tid = threadIdx.x;

    if (bx >= RT_NB) {
        if (bx < RT_NB + PREP_NB) {
            // ---- W fp32 -> bf16 (268 MB read, 134 MB write) ----
            const long g = (long)(bx - RT_NB) * 256 + tid;
            const long nt = (long)PREP_NB * 256;
            const long N8 = (long)NE * H_DIM * H_DIM / 8;  // 4,194,304 groups of 8
            const float4* w4 = (const float4*)w;
            uint4* wb4 = (uint4*)wb;
            for (long i = g; i < N8; i += nt) {
                float4 a = w4[i * 2];
                float4 b = w4[i * 2 + 1];
                uint4 o;
                o.x = pack_bf16x2(a.x, a.y);
                o.y = pack_bf16x2(a.z, a.w);
                o.z = pack_bf16x2(b.x, b.y);
                o.w = pack_bf16x2(b.z, b.w);
                wb4[i] = o;
            }
        } else {
            // ---- zero out[] (67 MB write) ----
            const long g = (long)(bx - RT_NB - PREP_NB) * 256 + tid;
            const long nt = (long)ZERO_NB * 256;
            const long N4 = (long)T_TOK * H_DIM / 4;  // 4,194,304 uint4
            uint4* o4 = (uint4*)out;
            const uint4 z = {0u, 0u, 0u, 0u};
            for (long i = g; i < N4; i += nt) o4[i] = z;
        }
        return;
    }

    // ---- router: 16 tokens/block, fused X fp32->bf16, fp32 logits,
    //      softmax-free top-2, per-block aggregated list append ----
    const float4* g4 = (const float4*)gate;
    for (int i = tid; i < NE * H_DIM / 4; i += 256) gs[i] = g4[i];
    __syncthreads();

    const int wave = tid >> 6, lane = tid & 63;

    for (int it = 0; it < 4; ++it) {
        const int tok = wave * 4 + it;               // 0..15 within block
        const int t = bx * 16 + tok;
        const float4* xr = (const float4*)(x + (long)t * H_DIM);
        ushort4* xw = (ushort4*)(xb + (long)t * H_DIM);
        float acc[NE];
#pragma unroll
        for (int e = 0; e < NE; ++e) acc[e] = 0.f;
#pragma unroll
        for (int i = 0; i < 8; ++i) {
            float4 xv = xr[i * 64 + lane];
            xw[i * 64 + lane] = make_ushort4(f32_to_bf16(xv.x), f32_to_bf16(xv.y),
                                             f32_to_bf16(xv.z), f32_to_bf16(xv.w));
#pragma unroll
            for (int e = 0; e < NE; ++e) {
                float4 gv = gs[e * 512 + i * 64 + lane];
                acc[e] += xv.x * gv.x + xv.y * gv.y + xv.z * gv.z + xv.w * gv.w;
            }
        }
#pragma unroll
        for (int e = 0; e < NE; ++e)
#pragma unroll
            for (int off = 32; off > 0; off >>= 1)
                acc[e] += __shfl_xor(acc[e], off, 64);

        if (lane == 0) {
            float l0 = -1e30f; int i0 = 0;
#pragma unroll
            for (int e = 0; e < NE; ++e)
                if (acc[e] > l0) { l0 = acc[e]; i0 = e; }
            float l1 = -1e30f; int i1 = 0;
#pragma unroll
            for (int e = 0; e < NE; ++e)
                if (e != i0 && acc[e] > l1) { l1 = acc[e]; i1 = e; }
            float e1v = __expf(l1 - l0);
            float inv = 1.f / (1.f + e1v);
#pragma unroll
            for (int e = 0; e < NE; ++e) logits[(long)t * NE + e] = acc[e];
            aExp[tok * 2] = i0;     aW[tok * 2] = inv;
            aExp[tok * 2 + 1] = i1; aW[tok * 2 + 1] = e1v * inv;
        }
    }
    __syncthreads();

    if (tid < NE) {
        const int e = tid;
        int c = 0;
#pragma unroll
        for (int k = 0; k < 32; ++k) c += (aExp[k] == e);
        if (c) {
            int pos = atomicAdd(&cnt[e], c);
            for (int k = 0; k < 32; ++k)
                if (aExp[k] == e) {
                    list[e * T_TOK + pos] = bx * 16 + (k >> 1);
                    wl[e * T_TOK + pos] = aW[k];
                    ++pos;
                }
        }
    }
}

// ---------------------------------------------------------------------------
// Kernel 3: grouped expert GEMM — round-0 proven structure (205 us steady):
// 128x128 tile, BK=64, single-buffered LDS (33 KiB -> 4 blocks/CU), 4 waves
// of 4x4 16x16x32 bf16 MFMA, XOR-swizzled LDS staging via global_load_lds.
// NEW: chunked XCD swizzle — the 16 col-tile blocks sharing one A-panel
// (same 128 gathered token rows, ~512 KB) are placed on the SAME XCD
// (consecutive-on-XCD blockIdx are {x, x+8, x+16, ...}), so the scattered
// token gather hits that XCD's L2 16x instead of 2x.
// ---------------------------------------------------------------------------
__global__ __launch_bounds__(256, 4) void moe_gemm(
        const unsigned short* __restrict__ xb, const unsigned short* __restrict__ wb,
        const int* __restrict__ cnt, const int* __restrict__ list,
        const float* __restrict__ wl, float* __restrict__ out) {
    __shared__ uint4 As[1024];  // 128 rows x 64 bf16 = 16 KiB
    __shared__ uint4 Bs[1024];
    __shared__ int tIdx[128];
    __shared__ float tw[128];

    // XCD-chunked bijective remap: hw XCD = blockIdx.x % 8.
    const int b0 = blockIdx.x;
    const int xcd  = b0 & 7;
    const int slot = b0 >> 3;                 // 0..1023 within XCD
    const int chunk = xcd * 64 + (slot >> 4); // 512 chunks of 16, 64 per XCD
    const int wg = (chunk << 4) | (slot & 15);

    const int e  = wg >> 10;         // 1024 blocks per expert
    const int rt = (wg >> 4) & 63;   // 64 row tiles
    const int ct = wg & 15;          // 16 col tiles (same chunk = same A-panel)
    const int n = cnt[e];
    const int row0 = rt << 7;
    if (row0 >= n) return;
    const int rv = min(128, n - row0);

    const int tid = threadIdx.x;
    if (tid < 128) {
        if (tid < rv) {
            tIdx[tid] = list[e * T_TOK + row0 + tid];
            tw[tid]   = wl[e * T_TOK + row0 + tid];
        } else { tIdx[tid] = 0; tw[tid] = 0.f; }
    }
    __syncthreads();

    const int wave = tid >> 6, lane = tid & 63;
    const int wm = (wave >> 1) << 6;   // 0 / 64
    const int wn = (wave & 1) << 6;    // 0 / 64
    const int quad = lane >> 4, l16 = lane & 15;

    f32x4 acc[4][4];
#pragma unroll
    for (int i = 0; i < 4; ++i)
#pragma unroll
        for (int j = 0; j < 4; ++j) acc[i][j] = (f32x4){0.f, 0.f, 0.f, 0.f};

    // Per-lane global sources for async staging: phys chunk p = i*256+wave*64+lane
    const unsigned short* aSrc[4];
    const unsigned short* bSrc[4];
    const long wbase = (long)e * H_DIM * H_DIM + (long)(ct * 128) * H_DIM;
#pragma unroll
    for (int i = 0; i < 4; ++i) {
        const int p = i * 256 + wave * 64 + lane;
        const int r = p >> 3;
        const int c = (p & 7) ^ (r & 7);   // logical k-chunk for this phys slot
        aSrc[i] = xb + (long)tIdx[r] * H_DIM + c * 8;
        bSrc[i] = wb + wbase + (long)r * H_DIM + c * 8;
    }

    for (int kt = 0; kt < H_DIM / 64; ++kt) {
        const int k0 = kt * 64;
#pragma unroll
        for (int i = 0; i < 4; ++i) {
            async_ld16(aSrc[i] + k0, &As[i * 256 + wave * 64]);
            async_ld16(bSrc[i] + k0, &Bs[i * 256 + wave * 64]);
        }
        __syncthreads();
#pragma unroll
        for (int ks = 0; ks < 2; ++ks) {
            s16x8 af[4], bfr[4];
            const int kc = ks * 4 + quad;
#pragma unroll
            for (int i = 0; i < 4; ++i) {
                int r = wm + i * 16 + l16;
                af[i] = ((const s16x8*)As)[(r << 3) | (kc ^ (r & 7))];
            }
#pragma unroll
            for (int j = 0; j < 4; ++j) {
                int d = wn + j * 16 + l16;
                bfr[j] = ((const s16x8*)Bs)[(d << 3) | (kc ^ (d & 7))];
            }
#pragma unroll
            for (int i = 0; i < 4; ++i)
#pragma unroll
                for (int j = 0; j < 4; ++j)
                    acc[i][j] = __builtin_amdgcn_mfma_f32_16x16x32_bf16(
                        af[i], bfr[j], acc[i][j], 0, 0, 0);
        }
        __syncthreads();
    }

    // Epilogue: C/D layout col = lane&15, row = quad*4 + reg.
    const int colbase = ct * 128 + wn;
#pragma unroll
    for (int i = 0; i < 4; ++i) {
        const int rbase = wm + i * 16 + quad * 4;
#pragma unroll
        for (int jr = 0; jr < 4; ++jr) {
            const int r = rbase + jr;
            if (r < rv) {
                const float wgt = tw[r];
                const long orow = (long)tIdx[r] * H_DIM + colbase;
#pragma unroll
                for (int j = 0; j < 4; ++j)
                    atomicAdd(&out[orow + j * 16 + l16], acc[i][j][jr] * wgt);
            }
        }
    }
}

// ---------------------------------------------------------------------------
extern "C" void kernel_launch(void* const* d_in, const int* in_sizes, int n_in,
                              void* d_out, int out_size, void* d_ws, size_t ws_size,
                              hipStream_t stream) {
    (void)in_sizes; (void)n_in; (void)out_size; (void)ws_size;
    const float* x    = (const float*)d_in[0];   // [T, H] fp32
    const float* gate = (const float*)d_in[1];   // [E, H] fp32
    const float* w    = (const float*)d_in[2];   // [E, H, H] fp32

    float* out    = (float*)d_out;                       // [T, H]
    float* logits = out + (size_t)T_TOK * H_DIM;         // [T, E]

    char* ws = (char*)d_ws;
    unsigned short* xb = (unsigned short*)(ws);                 // 33,554,432 B
    unsigned short* wb = (unsigned short*)(ws + 33554432);      // 67,108,864 B
    int*   cnt  = (int*)(ws + 100663296);                       // 32 B
    int*   list = (int*)(ws + 100663328);                       // 262,144 B
    float* wl   = (float*)(ws + 100925472);                     // 262,144 B

    hipMemsetAsync(cnt, 0, NE * sizeof(int), stream);
    pre_kernel<<<RT_NB + PREP_NB + ZERO_NB, 256, 0, stream>>>(
        x, gate, w, xb, wb, logits, out, cnt, list, wl);
    moe_gemm<<<8192, 256, 0, stream>>>(xb, wb, cnt, list, wl, out);
}

// Round 5
// 508.144 us; speedup vs baseline: 1.0242x; 1.0242x over previous
//
#include <hip/hip_runtime.h>
#include <hip/hip_bf16.h>

// Problem constants (B=4, S=2048, H=2048, E=8, K=2)
#define T_TOK 8192
#define H_DIM 2048
#define NE 8

typedef float f32x4 __attribute__((ext_vector_type(4)));
typedef short s16x8 __attribute__((ext_vector_type(8)));

typedef __attribute__((address_space(3))) unsigned int lds_uint;
typedef __attribute__((address_space(1))) const unsigned int glob_uint;

static __device__ __forceinline__ void async_ld16(const void* g, void* l) {
    // 64 lanes x 16B: global per-lane address -> LDS (wave-uniform base + lane*16)
    __builtin_amdgcn_global_load_lds((glob_uint*)g, (lds_uint*)l, 16, 0, 0);
}

static __device__ __forceinline__ unsigned short f32_to_bf16(float f) {
    unsigned int u = __builtin_bit_cast(unsigned int, f);
    unsigned int r = (u + 0x7FFFu + ((u >> 16) & 1u)) >> 16;
    return (unsigned short)r;
}

static __device__ __forceinline__ unsigned int pack_bf16x2(float lo, float hi) {
    return (unsigned int)f32_to_bf16(lo) | ((unsigned int)f32_to_bf16(hi) << 16);
}

// ---------------------------------------------------------------------------
// Fused pre-kernel, v2. Three block ranges overlap in one grid:
//   blocks [0,512):        router (16 tokens/block) — gate read via L2, NO
//                          64 KiB LDS stage (static LDS is reserved for EVERY
//                          block of a fused kernel; v1's gate LDS capped the
//                          whole grid at 2 blocks/CU and latency-starved the
//                          streaming blocks). Only 384 B LDS remains -> ~8
//                          blocks/CU, 32 waves/CU.
//   blocks [512,1536):     W fp32 -> bf16 convert (grid-stride, 32B ld/16B st)
//   blocks [1536,2048):    zero out[] (uint4 stores)
// 2048 blocks = one residency round at 8 blocks/CU. Router dispatched first.
// cnt[] zeroed by stream-ordered hipMemsetAsync before this kernel.
// ---------------------------------------------------------------------------
#define RT_NB 512
#define PREP_NB 1024
#define ZERO_NB 512

__global__ __launch_bounds__(256) void pre_kernel(
        const float* __restrict__ x, const float* __restrict__ gate,
        const float* __restrict__ w,
        unsigned short* __restrict__ xb, unsigned short* __restrict__ wb,
        float* __restrict__ logits, float* __restrict__ out,
        int* __restrict__ cnt, int* __restrict__ list, float* __restrict__ wl) {
    __shared__ int aExp[32];
    __shared__ float aW[32];

    const int bx = blockIdx.x;
    const int tid = threadIdx.x;

    if (bx >= RT_NB) {
        if (bx < RT_NB + PREP_NB) {
            // ---- W fp32 -> bf16 (268 MB read, 134 MB write) ----
            const long g = (long)(bx - RT_NB) * 256 + tid;
            const long nt = (long)PREP_NB * 256;
            const long N8 = (long)NE * H_DIM * H_DIM / 8;  // 4,194,304 groups of 8
            const float4* w4 = (const float4*)w;
            uint4* wb4 = (uint4*)wb;
            for (long i = g; i < N8; i += nt) {
                float4 a = w4[i * 2];
                float4 b = w4[i * 2 + 1];
                uint4 o;
                o.x = pack_bf16x2(a.x, a.y);
                o.y = pack_bf16x2(a.z, a.w);
                o.z = pack_bf16x2(b.x, b.y);
                o.w = pack_bf16x2(b.z, b.w);
                wb4[i] = o;
            }
        } else {
            // ---- zero out[] (67 MB write) ----
            const long g = (long)(bx - RT_NB - PREP_NB) * 256 + tid;
            const long nt = (long)ZERO_NB * 256;
            const long N4 = (long)T_TOK * H_DIM / 4;  // 4,194,304 uint4
            uint4* o4 = (uint4*)out;
            const uint4 z = {0u, 0u, 0u, 0u};
            for (long i = g; i < N4; i += nt) o4[i] = z;
        }
        return;
    }

    // ---- router: 16 tokens/block, fused X fp32->bf16, fp32 logits,
    //      softmax-free top-2, per-block aggregated list append.
    //      gate (64 KB, shared by all 512 blocks) is read through L2. ----
    const float4* g4 = (const float4*)gate;
    const int wave = tid >> 6, lane = tid & 63;

    for (int it = 0; it < 4; ++it) {
        const int tok = wave * 4 + it;               // 0..15 within block
        const int t = bx * 16 + tok;
        const float4* xr = (const float4*)(x + (long)t * H_DIM);
        ushort4* xw = (ushort4*)(xb + (long)t * H_DIM);
        float acc[NE];
#pragma unroll
        for (int e = 0; e < NE; ++e) acc[e] = 0.f;
#pragma unroll
        for (int i = 0; i < 8; ++i) {
            float4 xv = xr[i * 64 + lane];
            xw[i * 64 + lane] = make_ushort4(f32_to_bf16(xv.x), f32_to_bf16(xv.y),
                                             f32_to_bf16(xv.z), f32_to_bf16(xv.w));
#pragma unroll
            for (int e = 0; e < NE; ++e) {
                float4 gv = g4[e * 512 + i * 64 + lane];
                acc[e] += xv.x * gv.x + xv.y * gv.y + xv.z * gv.z + xv.w * gv.w;
            }
        }
#pragma unroll
        for (int e = 0; e < NE; ++e)
#pragma unroll
            for (int off = 32; off > 0; off >>= 1)
                acc[e] += __shfl_xor(acc[e], off, 64);

        if (lane == 0) {
            float l0 = -1e30f; int i0 = 0;
#pragma unroll
            for (int e = 0; e < NE; ++e)
                if (acc[e] > l0) { l0 = acc[e]; i0 = e; }
            float l1 = -1e30f; int i1 = 0;
#pragma unroll
            for (int e = 0; e < NE; ++e)
                if (e != i0 && acc[e] > l1) { l1 = acc[e]; i1 = e; }
            float e1v = __expf(l1 - l0);
            float inv = 1.f / (1.f + e1v);
#pragma unroll
            for (int e = 0; e < NE; ++e) logits[(long)t * NE + e] = acc[e];
            aExp[tok * 2] = i0;     aW[tok * 2] = inv;
            aExp[tok * 2 + 1] = i1; aW[tok * 2 + 1] = e1v * inv;
        }
    }
    __syncthreads();

    if (tid < NE) {
        const int e = tid;
        int c = 0;
#pragma unroll
        for (int k = 0; k < 32; ++k) c += (aExp[k] == e);
        if (c) {
            int pos = atomicAdd(&cnt[e], c);
            for (int k = 0; k < 32; ++k)
                if (aExp[k] == e) {
                    list[e * T_TOK + pos] = bx * 16 + (k >> 1);
                    wl[e * T_TOK + pos] = aW[k];
                    ++pos;
                }
        }
    }
}

// ---------------------------------------------------------------------------
// Kernel 3: grouped expert GEMM — exact round-0 proven structure (205 us):
// 128x128 tile, BK=64, single-buffered LDS (33 KiB -> 4 blocks/CU), 4 waves
// of 4x4 16x16x32 bf16 MFMA, XOR-swizzled LDS staging via global_load_lds,
// identity block mapping (XCD swizzle measured -10% in R4: fetch -32% but
// the kernel is latency/sync-bound, not fetch-bound — reverted).
// ---------------------------------------------------------------------------
__global__ __launch_bounds__(256, 4) void moe_gemm(
        const unsigned short* __restrict__ xb, const unsigned short* __restrict__ wb,
        const int* __restrict__ cnt, const int* __restrict__ list,
        const float* __restrict__ wl, float* __restrict__ out) {
    __shared__ uint4 As[1024];  // 128 rows x 64 bf16 = 16 KiB
    __shared__ uint4 Bs[1024];
    __shared__ int tIdx[128];
    __shared__ float tw[128];

    const int bx = blockIdx.x;
    const int e  = bx >> 10;         // 1024 blocks per expert
    const int rt = (bx >> 4) & 63;   // 64 row tiles
    const int ct = bx & 15;          // 16 col tiles
    const int n = cnt[e];
    const int row0 = rt << 7;
    if (row0 >= n) return;
    const int rv = min(128, n - row0);

    const int tid = threadIdx.x;
    if (tid < 128) {
        if (tid < rv) {
            tIdx[tid] = list[e * T_TOK + row0 + tid];
            tw[tid]   = wl[e * T_TOK + row0 + tid];
        } else { tIdx[tid] = 0; tw[tid] = 0.f; }
    }
    __syncthreads();

    const int wave = tid >> 6, lane = tid & 63;
    const int wm = (wave >> 1) << 6;   // 0 / 64
    const int wn = (wave & 1) << 6;    // 0 / 64
    const int quad = lane >> 4, l16 = lane & 15;

    f32x4 acc[4][4];
#pragma unroll
    for (int i = 0; i < 4; ++i)
#pragma unroll
        for (int j = 0; j < 4; ++j) acc[i][j] = (f32x4){0.f, 0.f, 0.f, 0.f};

    // Per-lane global sources for async staging: phys chunk p = i*256+wave*64+lane
    const unsigned short* aSrc[4];
    const unsigned short* bSrc[4];
    const long wbase = (long)e * H_DIM * H_DIM + (long)(ct * 128) * H_DIM;
#pragma unroll
    for (int i = 0; i < 4; ++i) {
        const int p = i * 256 + wave * 64 + lane;
        const int r = p >> 3;
        const int c = (p & 7) ^ (r & 7);   // logical k-chunk for this phys slot
        aSrc[i] = xb + (long)tIdx[r] * H_DIM + c * 8;
        bSrc[i] = wb + wbase + (long)r * H_DIM + c * 8;
    }

    for (int kt = 0; kt < H_DIM / 64; ++kt) {
        const int k0 = kt * 64;
#pragma unroll
        for (int i = 0; i < 4; ++i) {
            async_ld16(aSrc[i] + k0, &As[i * 256 + wave * 64]);
            async_ld16(bSrc[i] + k0, &Bs[i * 256 + wave * 64]);
        }
        __syncthreads();
#pragma unroll
        for (int ks = 0; ks < 2; ++ks) {
            s16x8 af[4], bfr[4];
            const int kc = ks * 4 + quad;
#pragma unroll
            for (int i = 0; i < 4; ++i) {
                int r = wm + i * 16 + l16;
                af[i] = ((const s16x8*)As)[(r << 3) | (kc ^ (r & 7))];
            }
#pragma unroll
            for (int j = 0; j < 4; ++j) {
                int d = wn + j * 16 + l16;
                bfr[j] = ((const s16x8*)Bs)[(d << 3) | (kc ^ (d & 7))];
            }
#pragma unroll
            for (int i = 0; i < 4; ++i)
#pragma unroll
                for (int j = 0; j < 4; ++j)
                    acc[i][j] = __builtin_amdgcn_mfma_f32_16x16x32_bf16(
                        af[i], bfr[j], acc[i][j], 0, 0, 0);
        }
        __syncthreads();
    }

    // Epilogue: C/D layout col = lane&15, row = quad*4 + reg.
    const int colbase = ct * 128 + wn;
#pragma unroll
    for (int i = 0; i < 4; ++i) {
        const int rbase = wm + i * 16 + quad * 4;
#pragma unroll
        for (int jr = 0; jr < 4; ++jr) {
            const int r = rbase + jr;
            if (r < rv) {
                const float wgt = tw[r];
                const long orow = (long)tIdx[r] * H_DIM + colbase;
#pragma unroll
                for (int j = 0; j < 4; ++j)
                    atomicAdd(&out[orow + j * 16 + l16], acc[i][j][jr] * wgt);
            }
        }
    }
}

// ---------------------------------------------------------------------------
extern "C" void kernel_launch(void* const* d_in, const int* in_sizes, int n_in,
                              void* d_out, int out_size, void* d_ws, size_t ws_size,
                              hipStream_t stream) {
    (void)in_sizes; (void)n_in; (void)out_size; (void)ws_size;
    const float* x    = (const float*)d_in[0];   // [T, H] fp32
    const float* gate = (const float*)d_in[1];   // [E, H] fp32
    const float* w    = (const float*)d_in[2];   // [E, H, H] fp32

    float* out    = (float*)d_out;                       // [T, H]
    float* logits = out + (size_t)T_TOK * H_DIM;         // [T, E]

    char* ws = (char*)d_ws;
    unsigned short* xb = (unsigned short*)(ws);                 // 33,554,432 B
    unsigned short* wb = (unsigned short*)(ws + 33554432);      // 67,108,864 B
    int*   cnt  = (int*)(ws + 100663296);                       // 32 B
    int*   list = (int*)(ws + 100663328);                       // 262,144 B
    float* wl   = (float*)(ws + 100925472);                     // 262,144 B

    hipMemsetAsync(cnt, 0, NE * sizeof(int), stream);
    pre_kernel<<<RT_NB + PREP_NB + ZERO_NB, 256, 0, stream>>>(
        x, gate, w, xb, wb, logits, out, cnt, list, wl);
    moe_gemm<<<8192, 256, 0, stream>>>(xb, wb, cnt, list, wl, out);
}